// Round 1
// baseline (89.318 us; speedup 1.0000x reference)
//
#include <hip/hip_runtime.h>

#define CUBIC_A (-0.75f)

__device__ __forceinline__ float cubic_w(float d) {
    float ad = fabsf(d);
    if (ad <= 1.0f) return ((CUBIC_A + 2.0f) * ad - (CUBIC_A + 3.0f)) * ad * ad + 1.0f;
    if (ad < 2.0f)  return CUBIC_A * (((ad - 5.0f) * ad + 8.0f) * ad - 4.0f);
    return 0.0f;
}

// GRIDS = [(8,32,32),(8,48,48),(4,64,64),(1,64,64)], weight (64,64,1024), dim=1024.
// One block per (grid, pixel). 256 threads; thread d4 owns float4 column d4.
// Blocks: [0,1024) g0 32x32 | [1024,3328) g1 48x48 | [3328,7424) g2 64x64 t=4 | [7424,11520) g3 64x64 t=1
__global__ __launch_bounds__(256) void posemb_add_kernel(
    const float4* __restrict__ x,     // (47104, 256) as float4
    const float4* __restrict__ wgt,   // (64*64, 256) as float4
    const float4* __restrict__ tw,    // (16, 256) as float4
    float4* __restrict__ out)         // (47104, 256) as float4
{
    const int b  = blockIdx.x;
    const int d4 = threadIdx.x;

    int t, out_hw, px;
    long rowbase;
    int ppf;
    bool interp;
    if (b < 1024)      { t = 8; out_hw = 32; px = b;        rowbase = 0;     ppf = 1024; interp = true;  }
    else if (b < 3328) { t = 8; out_hw = 48; px = b - 1024; rowbase = 8192;  ppf = 2304; interp = true;  }
    else if (b < 7424) { t = 4; out_hw = 64; px = b - 3328; rowbase = 26624; ppf = 4096; interp = false; }
    else               { t = 1; out_hw = 64; px = b - 7424; rowbase = 43008; ppf = 4096; interp = false; }

    float4 pe;
    if (!interp) {
        pe = wgt[(size_t)px * 256 + d4];
    } else {
        const int i = px / out_hw;
        const int j = px % out_hw;
        const float scale = 64.0f / (float)out_hw;
        const float si = ((float)i + 0.5f) * scale - 0.5f;
        const float sj = ((float)j + 0.5f) * scale - 0.5f;
        const int i0 = (int)floorf(si);
        const int j0 = (int)floorf(sj);
        int ih[4], iw[4];
        float wh[4], ww[4];
#pragma unroll
        for (int a = 0; a < 4; ++a) {
            int tp = i0 - 1 + a;
            wh[a] = cubic_w(si - (float)tp);
            ih[a] = min(63, max(0, tp));
            tp = j0 - 1 + a;
            ww[a] = cubic_w(sj - (float)tp);
            iw[a] = min(63, max(0, tp));
        }
        float ax = 0.f, ay = 0.f, az = 0.f, aw = 0.f;
#pragma unroll
        for (int a = 0; a < 4; ++a) {
            float rx = 0.f, ry = 0.f, rz = 0.f, rw = 0.f;
#pragma unroll
            for (int c = 0; c < 4; ++c) {
                const float4 v = wgt[(size_t)(ih[a] * 64 + iw[c]) * 256 + d4];
                rx = fmaf(ww[c], v.x, rx);
                ry = fmaf(ww[c], v.y, ry);
                rz = fmaf(ww[c], v.z, rz);
                rw = fmaf(ww[c], v.w, rw);
            }
            ax = fmaf(wh[a], rx, ax);
            ay = fmaf(wh[a], ry, ay);
            az = fmaf(wh[a], rz, az);
            aw = fmaf(wh[a], rw, aw);
        }
        pe = make_float4(ax, ay, az, aw);
    }

    if (t > 1) {
        for (int f = 0; f < t; ++f) {
            const size_t row = (size_t)rowbase + (size_t)f * ppf + px;
            const float4 xv = x[row * 256 + d4];
            const float4 tv = tw[(size_t)f * 256 + d4];
            out[row * 256 + d4] = make_float4(xv.x + pe.x + tv.x,
                                              xv.y + pe.y + tv.y,
                                              xv.z + pe.z + tv.z,
                                              xv.w + pe.w + tv.w);
        }
    } else {
        const size_t row = (size_t)rowbase + px;
        const float4 xv = x[row * 256 + d4];
        out[row * 256 + d4] = make_float4(xv.x + pe.x,
                                          xv.y + pe.y,
                                          xv.z + pe.z,
                                          xv.w + pe.w);
    }
}

extern "C" void kernel_launch(void* const* d_in, const int* in_sizes, int n_in,
                              void* d_out, int out_size, void* d_ws, size_t ws_size,
                              hipStream_t stream) {
    const float4* x   = (const float4*)d_in[0];
    const float4* wgt = (const float4*)d_in[1];
    const float4* tw  = (const float4*)d_in[2];
    float4* out = (float4*)d_out;
    // 1024 + 2304 + 4096 + 4096 = 11520 pixel-blocks
    posemb_add_kernel<<<11520, 256, 0, stream>>>(x, wgt, tw, out);
}